// Round 1
// 561.296 us; speedup vs baseline: 1.2674x; 1.2674x over previous
//
#include <hip/hip_runtime.h>
#include <cstdint>

#define LDD 4096
#define NT 64   // K tiles of 64

typedef __attribute__((ext_vector_type(8))) short short8;   // 8 bf16 (4 VGPRs)
typedef __attribute__((ext_vector_type(4))) float f32x4;    // MFMA accumulator

// round-to-nearest-even fp32 -> bf16 (finite inputs only)
__device__ __forceinline__ short f2bf(float f) {
  uint32_t u = __builtin_bit_cast(uint32_t, f);
  u += 0x7fffu + ((u >> 16) & 1u);
  return (short)(u >> 16);
}

// async global->LDS, 16B per lane. LDS dest is wave-uniform base + lane*16.
__device__ __forceinline__ void async16(const void* g, void* l) {
  __builtin_amdgcn_global_load_lds(
      (const __attribute__((address_space(1))) unsigned*)(uintptr_t)g,
      (__attribute__((address_space(3))) unsigned*)(uintptr_t)l,
      16, 0, 0);
}

// ---- prep: x fp32 -> x bf16 (row-major) + sq[i] = sum_f x[i,f]^2 (fp32) ----
__global__ __launch_bounds__(256)
void prep_rows(const float* __restrict__ x, short* __restrict__ xb,
               float* __restrict__ sq) {
  int row = blockIdx.x, tid = threadIdx.x;
  const float4* xr = (const float4*)(x + (size_t)row * LDD);
  short4* xo = (short4*)(xb + (size_t)row * LDD);
  float s = 0.f;
#pragma unroll
  for (int i = 0; i < 4; i++) {
    float4 v = xr[i * 256 + tid];
    s = fmaf(v.x, v.x, s); s = fmaf(v.y, v.y, s);
    s = fmaf(v.z, v.z, s); s = fmaf(v.w, v.w, s);
    short4 o; o.x = f2bf(v.x); o.y = f2bf(v.y); o.z = f2bf(v.z); o.w = f2bf(v.w);
    xo[i * 256 + tid] = o;
  }
#pragma unroll
  for (int off = 32; off > 0; off >>= 1) s += __shfl_down(s, off, 64);
  __shared__ float red[4];
  int lane = tid & 63, wv = tid >> 6;
  if (lane == 0) red[wv] = s;
  __syncthreads();
  if (tid == 0) sq[row] = red[0] + red[1] + red[2] + red[3];
}

// ---- transpose: x fp32 [B,F] -> xT bf16 [F,B], 64x64 LDS tiles ----
__global__ __launch_bounds__(256)
void transpose_bf16(const float* __restrict__ x, short* __restrict__ xT) {
  __shared__ float tile[64][65];
  int bx = blockIdx.x, by = blockIdx.y, tid = threadIdx.x;
  int tr = tid >> 4;          // 0..15
  int tc = (tid & 15) << 2;   // 0,4,..,60
#pragma unroll
  for (int i = 0; i < 4; i++) {
    int r = i * 16 + tr;
    float4 v = *(const float4*)(x + (size_t)(by * 64 + r) * LDD + bx * 64 + tc);
    tile[r][tc + 0] = v.x; tile[r][tc + 1] = v.y;
    tile[r][tc + 2] = v.z; tile[r][tc + 3] = v.w;
  }
  __syncthreads();
#pragma unroll
  for (int i = 0; i < 4; i++) {
    int fr = i * 16 + tr;     // f index within tile
    short4 o;
    o.x = f2bf(tile[tc + 0][fr]); o.y = f2bf(tile[tc + 1][fr]);
    o.z = f2bf(tile[tc + 2][fr]); o.w = f2bf(tile[tc + 3][fr]);
    *(short4*)(xT + (size_t)(bx * 64 + fr) * LDD + by * 64 + tc) = o;
  }
}

// ---- elementwise fp32 -> bf16 convert (W_out) ----
__global__ __launch_bounds__(256)
void conv_bf16(const float* __restrict__ w, short* __restrict__ wb) {
  int i = blockIdx.x * 256 + threadIdx.x;
  float4 v = ((const float4*)w)[i];
  short4 o; o.x = f2bf(v.x); o.y = f2bf(v.y); o.z = f2bf(v.z); o.w = f2bf(v.w);
  ((short4*)wb)[i] = o;
}

// ============================================================================
// 256x256-tile 8-phase NT GEMM (m201 template, plain HIP).
//   C[M,N] = A[M,K] * Bt[N,K]^T, M=N=K=4096, BK=64, 512 threads (8 waves 2x4),
//   per-wave 128x64 output, LDS 128KB double-buffered, chunk-XOR swizzle,
//   counted vmcnt(4) once per K-tile, setprio(1) around MFMA clusters.
// MODE 0: gram epilogue  (extra = Wrbf, sq used), bf16 out
// MODE 1: plain bf16 out
// MODE 2: fp32 out + bias (extra = bias)
// ============================================================================
template <int MODE>
__global__ __launch_bounds__(512, 2)
void gemm256(const short* __restrict__ A, const short* __restrict__ Bt,
             short* __restrict__ outB, float* __restrict__ outF,
             const float* __restrict__ extra, const float* __restrict__ sq) {
  __shared__ __attribute__((aligned(16))) char smem[131072];
  const int tid = threadIdx.x;

  // XCD-bijective block swizzle: grid 256 = 16x16, nwg%8==0
  int bid = blockIdx.x;
  int lin = (bid & 7) * 32 + (bid >> 3);
  const int rb = (lin >> 4) * 256;
  const int cb = (lin & 15) * 256;

  // staging: LDS chunk s (16B) of a 128x8-chunk half-tile holds global chunk
  // (r = s>>3, c = (s&7) ^ (r&7)). global src pre-swizzled, LDS dest linear.
  const int s0 = tid, s1 = 512 + tid;
  const int r0 = s0 >> 3, c0 = (s0 & 7) ^ (r0 & 7);
  const int r1 = s1 >> 3, c1 = (s1 & 7) ^ (r1 & 7);
  const size_t go0 = (size_t)r0 * LDD + (size_t)(c0 << 3);
  const size_t go1 = (size_t)r1 * LDD + (size_t)(c1 << 3);

  // half IDs / LDS offsets: 0=B0@0, 1=B1@16K, 2=A0@32K, 3=A1@48K (per buffer)
  const short* gB0 = Bt + (size_t)cb * LDD;
  const short* gB1 = Bt + (size_t)(cb + 128) * LDD;
  const short* gA0 = A + (size_t)rb * LDD;
  const short* gA1 = A + (size_t)(rb + 128) * LDD;
  char* lst = smem + tid * 16;

  auto stage = [&](const short* g, int tt, int half) {
    const short* gp = g + (size_t)tt * 64;
    char* l = lst + ((tt & 1) << 16) + (half << 14);
    async16(gp + go0, l);
    async16(gp + go1, l + 8192);
  };

  // wave/fragment coords
  const int lane = tid & 63;
  const int wv = tid >> 6;        // 0..7
  const int wm = wv >> 2;         // 0..1  (M half)
  const int wn = wv & 3;          // 0..3  (N quarter)
  const int fr = lane & 15;
  const int fq = lane >> 4;
  const int arow = fr * 128;                       // + m*2048 (+8192 for m4-7)
  const int brow = ((wn & 1) * 64 + fr) * 128;     // + n*2048
  const int sx0 = ((fq ^ (fr & 7)) << 4);          // kk=0 chunk, swizzled
  const int sx1 = (((4 + fq) ^ (fr & 7)) << 4);    // kk=1 chunk, swizzled
  const int abase = 32768 + (wm << 14);
  const int bbase = (wn >> 1) << 14;

  f32x4 acc[8][4];
#pragma unroll
  for (int m = 0; m < 8; ++m)
#pragma unroll
    for (int n = 0; n < 4; ++n) acc[m][n] = {0.f, 0.f, 0.f, 0.f};

  // prologue: tile0 fully + tile1 B halves -> steady-state pipeline depth
  stage(gB0, 0, 0); stage(gB1, 0, 1); stage(gA0, 0, 2); stage(gA1, 0, 3);
  stage(gB0, 1, 0); stage(gB1, 1, 1);
  asm volatile("s_waitcnt vmcnt(4)" ::: "memory");
  __builtin_amdgcn_s_barrier();

  short8 av[4][2], bv[4][2];

  for (int t = 0; t < NT; ++t) {
    const int bufo = (t & 1) << 16;
    const char* ab = smem + bufo + abase;
    const char* bb = smem + bufo + bbase;

    // ---- P1: ds_read bv(all 4n x 2kk) + av(m0-3); stage (t+1) A0 ----
#pragma unroll
    for (int n = 0; n < 4; ++n) {
      bv[n][0] = *(const short8*)(bb + brow + n * 2048 + sx0);
      bv[n][1] = *(const short8*)(bb + brow + n * 2048 + sx1);
    }
#pragma unroll
    for (int m = 0; m < 4; ++m) {
      av[m][0] = *(const short8*)(ab + arow + m * 2048 + sx0);
      av[m][1] = *(const short8*)(ab + arow + m * 2048 + sx1);
    }
    if (t + 1 < NT) stage(gA0, t + 1, 2);
    __builtin_amdgcn_s_barrier();
    asm volatile("s_waitcnt lgkmcnt(0)" ::: "memory");
    __builtin_amdgcn_s_setprio(1);
#pragma unroll
    for (int m = 0; m < 4; ++m)
#pragma unroll
      for (int n = 0; n < 2; ++n)
#pragma unroll
        for (int kk = 0; kk < 2; ++kk)
          acc[m][n] = __builtin_amdgcn_mfma_f32_16x16x32_bf16(
              av[m][kk], bv[n][kk], acc[m][n], 0, 0, 0);
    __builtin_amdgcn_s_setprio(0);
    __builtin_amdgcn_s_barrier();

    // ---- P2: stage (t+1) A1; mfma m0-3 x n2-3 ----
    if (t + 1 < NT) stage(gA1, t + 1, 3);
    __builtin_amdgcn_s_barrier();
    __builtin_amdgcn_s_setprio(1);
#pragma unroll
    for (int m = 0; m < 4; ++m)
#pragma unroll
      for (int n = 2; n < 4; ++n)
#pragma unroll
        for (int kk = 0; kk < 2; ++kk)
          acc[m][n] = __builtin_amdgcn_mfma_f32_16x16x32_bf16(
              av[m][kk], bv[n][kk], acc[m][n], 0, 0, 0);
    __builtin_amdgcn_s_setprio(0);
    __builtin_amdgcn_s_barrier();

    // ---- P3: ds_read av(m4-7); stage (t+2) B0; mfma m4-7 x n0-1 ----
    // (B0 region of this buffer was fully read in P1, barrier-protected)
#pragma unroll
    for (int m = 0; m < 4; ++m) {
      av[m][0] = *(const short8*)(ab + 8192 + arow + m * 2048 + sx0);
      av[m][1] = *(const short8*)(ab + 8192 + arow + m * 2048 + sx1);
    }
    if (t + 2 < NT) stage(gB0, t + 2, 0);
    __builtin_amdgcn_s_barrier();
    asm volatile("s_waitcnt lgkmcnt(0)" ::: "memory");
    __builtin_amdgcn_s_setprio(1);
#pragma unroll
    for (int m = 0; m < 4; ++m)
#pragma unroll
      for (int n = 0; n < 2; ++n)
#pragma unroll
        for (int kk = 0; kk < 2; ++kk)
          acc[4 + m][n] = __builtin_amdgcn_mfma_f32_16x16x32_bf16(
              av[m][kk], bv[n][kk], acc[4 + m][n], 0, 0, 0);
    __builtin_amdgcn_s_setprio(0);
    __builtin_amdgcn_s_barrier();

    // ---- P4: stage (t+2) B1; mfma m4-7 x n2-3; counted vmcnt ----
    if (t + 2 < NT) stage(gB1, t + 2, 1);
    __builtin_amdgcn_s_barrier();
    __builtin_amdgcn_s_setprio(1);
#pragma unroll
    for (int m = 0; m < 4; ++m)
#pragma unroll
      for (int n = 2; n < 4; ++n)
#pragma unroll
        for (int kk = 0; kk < 2; ++kk)
          acc[4 + m][n] = __builtin_amdgcn_mfma_f32_16x16x32_bf16(
              av[m][kk], bv[n][kk], acc[4 + m][n], 0, 0, 0);
    __builtin_amdgcn_s_setprio(0);
    if (t + 2 < NT) asm volatile("s_waitcnt vmcnt(4)" ::: "memory");
    else            asm volatile("s_waitcnt vmcnt(0)" ::: "memory");
    __builtin_amdgcn_s_barrier();
  }

  // ---- epilogue ----
  const int orow = rb + wm * 128 + fq * 4;   // + m*16 + rr
  const int ocol = cb + wn * 64 + fr;        // + n*16
  if (MODE == 0) {
    float sqc[4];
#pragma unroll
    for (int n = 0; n < 4; ++n) sqc[n] = sq[ocol + n * 16];
#pragma unroll
    for (int m = 0; m < 8; ++m) {
#pragma unroll
      for (int rr = 0; rr < 4; ++rr) {
        int row = orow + m * 16 + rr;
        float sqr = sq[row];
#pragma unroll
        for (int n = 0; n < 4; ++n) {
          size_t idx = (size_t)row * LDD + ocol + n * 16;
          float d2 = sqr + sqc[n] - 2.0f * acc[m][n][rr];
          float d = sqrtf(fmaxf(d2, 0.f));
          outB[idx] = f2bf(__expf(-fabsf(extra[idx]) * d));
        }
      }
    }
  } else if (MODE == 1) {
#pragma unroll
    for (int m = 0; m < 8; ++m)
#pragma unroll
      for (int rr = 0; rr < 4; ++rr) {
        int row = orow + m * 16 + rr;
#pragma unroll
        for (int n = 0; n < 4; ++n)
          outB[(size_t)row * LDD + ocol + n * 16] = f2bf(acc[m][n][rr]);
      }
  } else {
    float bc[4];
#pragma unroll
    for (int n = 0; n < 4; ++n) bc[n] = extra[ocol + n * 16];
#pragma unroll
    for (int m = 0; m < 8; ++m)
#pragma unroll
      for (int rr = 0; rr < 4; ++rr) {
        int row = orow + m * 16 + rr;
#pragma unroll
        for (int n = 0; n < 4; ++n)
          outF[(size_t)row * LDD + ocol + n * 16] = acc[m][n][rr] + bc[n];
      }
  }
}

extern "C" void kernel_launch(void* const* d_in, const int* in_sizes, int n_in,
                              void* d_out, int out_size, void* d_ws, size_t ws_size,
                              hipStream_t stream) {
  const float* x    = (const float*)d_in[0];
  const float* Wrbf = (const float*)d_in[1];
  const float* Wout = (const float*)d_in[2];
  const float* bout = (const float*)d_in[3];
  float* out = (float*)d_out;

  char* ws = (char*)d_ws;
  short* xb    = (short*)ws;                               // 32 MB
  float* sq    = (float*)(ws + (size_t)32 * 1024 * 1024);  // 16 KB
  short* woutb = (short*)(ws + (size_t)32 * 1024 * 1024);  // 32 MB (after gram)
  short* gram  = (short*)d_out;                            // 32 MB
  short* xT    = (short*)((char*)d_out + (size_t)32 * 1024 * 1024);  // 32 MB
  short* mixed = xb;                                       // reuse after gram

  prep_rows<<<LDD, 256, 0, stream>>>(x, xb, sq);
  transpose_bf16<<<dim3(64, 64), 256, 0, stream>>>(x, xT);
  // gram[i,j] = exp(-|Wrbf[i,j]| * ||x_i - x_j||)  (full grid, fused epilogue)
  gemm256<0><<<256, 512, 0, stream>>>(xb, xb, gram, nullptr, Wrbf, sq);
  // mixed = gram @ x   (B^T operand = xT)
  gemm256<1><<<256, 512, 0, stream>>>(gram, xT, mixed, nullptr, nullptr, nullptr);
  conv_bf16<<<LDD * LDD / 4 / 256, 256, 0, stream>>>(Wout, woutb);
  // out = mixed @ W_out^T + b_out
  gemm256<2><<<256, 512, 0, stream>>>(mixed, woutb, nullptr, out, bout, nullptr);
}

// Round 2
// 541.454 us; speedup vs baseline: 1.3138x; 1.0366x over previous
//
#include <hip/hip_runtime.h>
#include <cstdint>

#define LDD 4096
#define NT 64   // K tiles of 64

typedef __attribute__((ext_vector_type(8))) short short8;   // 8 bf16 (4 VGPRs)
typedef __attribute__((ext_vector_type(4))) float f32x4;    // MFMA accumulator

// round-to-nearest-even fp32 -> bf16 (finite inputs only)
__device__ __forceinline__ short f2bf(float f) {
  uint32_t u = __builtin_bit_cast(uint32_t, f);
  u += 0x7fffu + ((u >> 16) & 1u);
  return (short)(u >> 16);
}

// async global->LDS, 16B per lane. LDS dest is wave-uniform base + lane*16.
__device__ __forceinline__ void async16(const void* g, void* l) {
  __builtin_amdgcn_global_load_lds(
      (const __attribute__((address_space(1))) unsigned*)(uintptr_t)g,
      (__attribute__((address_space(3))) unsigned*)(uintptr_t)l,
      16, 0, 0);
}

// ---- prep: x fp32 -> x bf16 (row-major) + sq[i] = sum_f x[i,f]^2 (fp32) ----
__global__ __launch_bounds__(256)
void prep_rows(const float* __restrict__ x, short* __restrict__ xb,
               float* __restrict__ sq) {
  int row = blockIdx.x, tid = threadIdx.x;
  const float4* xr = (const float4*)(x + (size_t)row * LDD);
  short4* xo = (short4*)(xb + (size_t)row * LDD);
  float s = 0.f;
#pragma unroll
  for (int i = 0; i < 4; i++) {
    float4 v = xr[i * 256 + tid];
    s = fmaf(v.x, v.x, s); s = fmaf(v.y, v.y, s);
    s = fmaf(v.z, v.z, s); s = fmaf(v.w, v.w, s);
    short4 o; o.x = f2bf(v.x); o.y = f2bf(v.y); o.z = f2bf(v.z); o.w = f2bf(v.w);
    xo[i * 256 + tid] = o;
  }
#pragma unroll
  for (int off = 32; off > 0; off >>= 1) s += __shfl_down(s, off, 64);
  __shared__ float red[4];
  int lane = tid & 63, wv = tid >> 6;
  if (lane == 0) red[wv] = s;
  __syncthreads();
  if (tid == 0) sq[row] = red[0] + red[1] + red[2] + red[3];
}

// ---- transpose: x fp32 [B,F] -> xT bf16 [F,B], 64x64 LDS tiles ----
__global__ __launch_bounds__(256)
void transpose_bf16(const float* __restrict__ x, short* __restrict__ xT) {
  __shared__ float tile[64][65];
  int bx = blockIdx.x, by = blockIdx.y, tid = threadIdx.x;
  int tr = tid >> 4;          // 0..15
  int tc = (tid & 15) << 2;   // 0,4,..,60
#pragma unroll
  for (int i = 0; i < 4; i++) {
    int r = i * 16 + tr;
    float4 v = *(const float4*)(x + (size_t)(by * 64 + r) * LDD + bx * 64 + tc);
    tile[r][tc + 0] = v.x; tile[r][tc + 1] = v.y;
    tile[r][tc + 2] = v.z; tile[r][tc + 3] = v.w;
  }
  __syncthreads();
#pragma unroll
  for (int i = 0; i < 4; i++) {
    int fr = i * 16 + tr;     // f index within tile
    short4 o;
    o.x = f2bf(tile[tc + 0][fr]); o.y = f2bf(tile[tc + 1][fr]);
    o.z = f2bf(tile[tc + 2][fr]); o.w = f2bf(tile[tc + 3][fr]);
    *(short4*)(xT + (size_t)(bx * 64 + fr) * LDD + by * 64 + tc) = o;
  }
}

// ---- elementwise fp32 -> bf16 convert (W_out) ----
__global__ __launch_bounds__(256)
void conv_bf16(const float* __restrict__ w, short* __restrict__ wb) {
  int i = blockIdx.x * 256 + threadIdx.x;
  float4 v = ((const float4*)w)[i];
  short4 o; o.x = f2bf(v.x); o.y = f2bf(v.y); o.z = f2bf(v.z); o.w = f2bf(v.w);
  ((short4*)wb)[i] = o;
}

// ============================================================================
// 256x256-tile 8-phase NT GEMM (m201 template, plain HIP).
//   C[M,N] = A[M,K] * Bt[N,K]^T, M=N=K=4096, BK=64, 512 threads (8 waves 2x4),
//   per-wave 128x64 output, LDS 128KB double-buffered, chunk-XOR swizzle,
//   counted vmcnt(4) once per K-tile, setprio(1) around MFMA clusters.
// R2 changes vs R1:
//  - kk-OUTER mfma ordering (dep distance 8, was back-to-back dependent pairs)
//  - ds_reads redistributed P1:12 / P2:4 / P3:8 / P4:0 (was 16/0/8/0),
//    with the template's lgkmcnt(8) pre-barrier throttle in P1.
// MODE 0: gram epilogue  (extra = Wrbf, sq used), bf16 out
// MODE 1: plain bf16 out
// MODE 2: fp32 out + bias (extra = bias)
// ============================================================================
template <int MODE>
__global__ __launch_bounds__(512, 2)
void gemm256(const short* __restrict__ A, const short* __restrict__ Bt,
             short* __restrict__ outB, float* __restrict__ outF,
             const float* __restrict__ extra, const float* __restrict__ sq) {
  __shared__ __attribute__((aligned(16))) char smem[131072];
  const int tid = threadIdx.x;

  // XCD-bijective block swizzle: grid 256 = 16x16, nwg%8==0
  int bid = blockIdx.x;
  int lin = (bid & 7) * 32 + (bid >> 3);
  const int rb = (lin >> 4) * 256;
  const int cb = (lin & 15) * 256;

  // staging: LDS chunk s (16B) of a 128x8-chunk half-tile holds global chunk
  // (r = s>>3, c = (s&7) ^ (r&7)). global src pre-swizzled, LDS dest linear.
  const int s0 = tid, s1 = 512 + tid;
  const int r0 = s0 >> 3, c0 = (s0 & 7) ^ (r0 & 7);
  const int r1 = s1 >> 3, c1 = (s1 & 7) ^ (r1 & 7);
  const size_t go0 = (size_t)r0 * LDD + (size_t)(c0 << 3);
  const size_t go1 = (size_t)r1 * LDD + (size_t)(c1 << 3);

  // half IDs / LDS offsets: 0=B0@0, 1=B1@16K, 2=A0@32K, 3=A1@48K (per buffer)
  const short* gB0 = Bt + (size_t)cb * LDD;
  const short* gB1 = Bt + (size_t)(cb + 128) * LDD;
  const short* gA0 = A + (size_t)rb * LDD;
  const short* gA1 = A + (size_t)(rb + 128) * LDD;
  char* lst = smem + tid * 16;

  auto stage = [&](const short* g, int tt, int half) {
    const short* gp = g + (size_t)tt * 64;
    char* l = lst + ((tt & 1) << 16) + (half << 14);
    async16(gp + go0, l);
    async16(gp + go1, l + 8192);
  };

  // wave/fragment coords
  const int lane = tid & 63;
  const int wv = tid >> 6;        // 0..7
  const int wm = wv >> 2;         // 0..1  (M half)
  const int wn = wv & 3;          // 0..3  (N quarter)
  const int fr = lane & 15;
  const int fq = lane >> 4;
  const int arow = fr * 128;                       // + m*2048 (+8192 for m4-7)
  const int brow = ((wn & 1) * 64 + fr) * 128;     // + n*2048
  const int sx0 = ((fq ^ (fr & 7)) << 4);          // kk=0 chunk, swizzled
  const int sx1 = (((4 + fq) ^ (fr & 7)) << 4);    // kk=1 chunk, swizzled
  const int abase = 32768 + (wm << 14);
  const int bbase = (wn >> 1) << 14;

  f32x4 acc[8][4];
#pragma unroll
  for (int m = 0; m < 8; ++m)
#pragma unroll
    for (int n = 0; n < 4; ++n) acc[m][n] = {0.f, 0.f, 0.f, 0.f};

  // prologue: tile0 fully + tile1 B halves -> steady-state pipeline depth
  stage(gB0, 0, 0); stage(gB1, 0, 1); stage(gA0, 0, 2); stage(gA1, 0, 3);
  stage(gB0, 1, 0); stage(gB1, 1, 1);
  asm volatile("s_waitcnt vmcnt(4)" ::: "memory");
  __builtin_amdgcn_s_barrier();

  short8 av[4][2], bv[4][2];

  for (int t = 0; t < NT; ++t) {
    const int bufo = (t & 1) << 16;
    const char* ab = smem + bufo + abase;
    const char* bb = smem + bufo + bbase;

    // ---- P1: ds_read bv[0..1] + av[m0-3] (12 reads); stage (t+1) A0;
    //          mfma Q00 (m0-3 x n0-1) ----
#pragma unroll
    for (int n = 0; n < 2; ++n) {
      bv[n][0] = *(const short8*)(bb + brow + n * 2048 + sx0);
      bv[n][1] = *(const short8*)(bb + brow + n * 2048 + sx1);
    }
#pragma unroll
    for (int m = 0; m < 4; ++m) {
      av[m][0] = *(const short8*)(ab + arow + m * 2048 + sx0);
      av[m][1] = *(const short8*)(ab + arow + m * 2048 + sx1);
    }
    if (t + 1 < NT) stage(gA0, t + 1, 2);
    asm volatile("s_waitcnt lgkmcnt(8)" ::: "memory");
    __builtin_amdgcn_s_barrier();
    asm volatile("s_waitcnt lgkmcnt(0)" ::: "memory");
    __builtin_amdgcn_s_setprio(1);
#pragma unroll
    for (int kk = 0; kk < 2; ++kk)
#pragma unroll
      for (int m = 0; m < 4; ++m)
#pragma unroll
        for (int n = 0; n < 2; ++n)
          acc[m][n] = __builtin_amdgcn_mfma_f32_16x16x32_bf16(
              av[m][kk], bv[n][kk], acc[m][n], 0, 0, 0);
    __builtin_amdgcn_s_setprio(0);
    __builtin_amdgcn_s_barrier();

    // ---- P2: ds_read bv[2..3] (4 reads); stage (t+1) A1;
    //          mfma Q01 (m0-3 x n2-3) ----
#pragma unroll
    for (int n = 2; n < 4; ++n) {
      bv[n][0] = *(const short8*)(bb + brow + n * 2048 + sx0);
      bv[n][1] = *(const short8*)(bb + brow + n * 2048 + sx1);
    }
    if (t + 1 < NT) stage(gA1, t + 1, 3);
    __builtin_amdgcn_s_barrier();
    asm volatile("s_waitcnt lgkmcnt(0)" ::: "memory");
    __builtin_amdgcn_s_setprio(1);
#pragma unroll
    for (int kk = 0; kk < 2; ++kk)
#pragma unroll
      for (int m = 0; m < 4; ++m)
#pragma unroll
        for (int n = 2; n < 4; ++n)
          acc[m][n] = __builtin_amdgcn_mfma_f32_16x16x32_bf16(
              av[m][kk], bv[n][kk], acc[m][n], 0, 0, 0);
    __builtin_amdgcn_s_setprio(0);
    __builtin_amdgcn_s_barrier();

    // ---- P3: ds_read av[m4-7] (8 reads); stage (t+2) B0;
    //          mfma Q10 (m4-7 x n0-1) ----
    // (B0 region of this buffer fully read by end of P2, barrier-protected)
#pragma unroll
    for (int m = 0; m < 4; ++m) {
      av[m][0] = *(const short8*)(ab + 8192 + arow + m * 2048 + sx0);
      av[m][1] = *(const short8*)(ab + 8192 + arow + m * 2048 + sx1);
    }
    if (t + 2 < NT) stage(gB0, t + 2, 0);
    __builtin_amdgcn_s_barrier();
    asm volatile("s_waitcnt lgkmcnt(0)" ::: "memory");
    __builtin_amdgcn_s_setprio(1);
#pragma unroll
    for (int kk = 0; kk < 2; ++kk)
#pragma unroll
      for (int m = 0; m < 4; ++m)
#pragma unroll
        for (int n = 0; n < 2; ++n)
          acc[4 + m][n] = __builtin_amdgcn_mfma_f32_16x16x32_bf16(
              av[m][kk], bv[n][kk], acc[4 + m][n], 0, 0, 0);
    __builtin_amdgcn_s_setprio(0);
    __builtin_amdgcn_s_barrier();

    // ---- P4: stage (t+2) B1; mfma Q11 (m4-7 x n2-3); counted vmcnt ----
    if (t + 2 < NT) stage(gB1, t + 2, 1);
    __builtin_amdgcn_s_barrier();
    __builtin_amdgcn_s_setprio(1);
#pragma unroll
    for (int kk = 0; kk < 2; ++kk)
#pragma unroll
      for (int m = 0; m < 4; ++m)
#pragma unroll
        for (int n = 2; n < 4; ++n)
          acc[4 + m][n] = __builtin_amdgcn_mfma_f32_16x16x32_bf16(
              av[m][kk], bv[n][kk], acc[4 + m][n], 0, 0, 0);
    __builtin_amdgcn_s_setprio(0);
    if (t + 2 < NT) asm volatile("s_waitcnt vmcnt(4)" ::: "memory");
    else            asm volatile("s_waitcnt vmcnt(0)" ::: "memory");
    __builtin_amdgcn_s_barrier();
  }

  // ---- epilogue ----
  const int orow = rb + wm * 128 + fq * 4;   // + m*16 + rr
  const int ocol = cb + wn * 64 + fr;        // + n*16
  if (MODE == 0) {
    float sqc[4];
#pragma unroll
    for (int n = 0; n < 4; ++n) sqc[n] = sq[ocol + n * 16];
#pragma unroll
    for (int m = 0; m < 8; ++m) {
#pragma unroll
      for (int rr = 0; rr < 4; ++rr) {
        int row = orow + m * 16 + rr;
        float sqr = sq[row];
#pragma unroll
        for (int n = 0; n < 4; ++n) {
          size_t idx = (size_t)row * LDD + ocol + n * 16;
          float d2 = sqr + sqc[n] - 2.0f * acc[m][n][rr];
          float d = sqrtf(fmaxf(d2, 0.f));
          outB[idx] = f2bf(__expf(-fabsf(extra[idx]) * d));
        }
      }
    }
  } else if (MODE == 1) {
#pragma unroll
    for (int m = 0; m < 8; ++m)
#pragma unroll
      for (int rr = 0; rr < 4; ++rr) {
        int row = orow + m * 16 + rr;
#pragma unroll
        for (int n = 0; n < 4; ++n)
          outB[(size_t)row * LDD + ocol + n * 16] = f2bf(acc[m][n][rr]);
      }
  } else {
    float bc[4];
#pragma unroll
    for (int n = 0; n < 4; ++n) bc[n] = extra[ocol + n * 16];
#pragma unroll
    for (int m = 0; m < 8; ++m)
#pragma unroll
      for (int rr = 0; rr < 4; ++rr) {
        int row = orow + m * 16 + rr;
#pragma unroll
        for (int n = 0; n < 4; ++n)
          outF[(size_t)row * LDD + ocol + n * 16] = acc[m][n][rr] + bc[n];
      }
  }
}

extern "C" void kernel_launch(void* const* d_in, const int* in_sizes, int n_in,
                              void* d_out, int out_size, void* d_ws, size_t ws_size,
                              hipStream_t stream) {
  const float* x    = (const float*)d_in[0];
  const float* Wrbf = (const float*)d_in[1];
  const float* Wout = (const float*)d_in[2];
  const float* bout = (const float*)d_in[3];
  float* out = (float*)d_out;

  char* ws = (char*)d_ws;
  short* xb    = (short*)ws;                               // 32 MB
  float* sq    = (float*)(ws + (size_t)32 * 1024 * 1024);  // 16 KB
  short* woutb = (short*)(ws + (size_t)32 * 1024 * 1024);  // 32 MB (after gram)
  short* gram  = (short*)d_out;                            // 32 MB
  short* xT    = (short*)((char*)d_out + (size_t)32 * 1024 * 1024);  // 32 MB
  short* mixed = xb;                                       // reuse after gram

  prep_rows<<<LDD, 256, 0, stream>>>(x, xb, sq);
  transpose_bf16<<<dim3(64, 64), 256, 0, stream>>>(x, xT);
  // gram[i,j] = exp(-|Wrbf[i,j]| * ||x_i - x_j||)  (full grid, fused epilogue)
  gemm256<0><<<256, 512, 0, stream>>>(xb, xb, gram, nullptr, Wrbf, sq);
  // mixed = gram @ x   (B^T operand = xT)
  gemm256<1><<<256, 512, 0, stream>>>(gram, xT, mixed, nullptr, nullptr, nullptr);
  conv_bf16<<<LDD * LDD / 4 / 256, 256, 0, stream>>>(Wout, woutb);
  // out = mixed @ W_out^T + b_out
  gemm256<2><<<256, 512, 0, stream>>>(mixed, woutb, nullptr, out, bout, nullptr);
}

// Round 4
// 517.372 us; speedup vs baseline: 1.3750x; 1.0465x over previous
//
#include <hip/hip_runtime.h>
#include <cstdint>

#define LDD 4096
#define NT 64   // K tiles of 64

typedef __attribute__((ext_vector_type(8))) short short8;   // 8 bf16 (4 VGPRs)
typedef __attribute__((ext_vector_type(4))) float f32x4;    // MFMA accumulator

// round-to-nearest-even fp32 -> bf16 (finite inputs only)
__device__ __forceinline__ short f2bf(float f) {
  uint32_t u = __builtin_bit_cast(uint32_t, f);
  u += 0x7fffu + ((u >> 16) & 1u);
  return (short)(u >> 16);
}

// async global->LDS, 16B per lane. LDS dest is wave-uniform base + lane*16.
__device__ __forceinline__ void async16(const void* g, void* l) {
  __builtin_amdgcn_global_load_lds(
      (const __attribute__((address_space(1))) unsigned*)(uintptr_t)g,
      (__attribute__((address_space(3))) unsigned*)(uintptr_t)l,
      16, 0, 0);
}

// ---- prep: x fp32 -> x bf16 (row-major) + sq[i] = sum_f x[i,f]^2 (fp32) ----
__global__ __launch_bounds__(256)
void prep_rows(const float* __restrict__ x, short* __restrict__ xb,
               float* __restrict__ sq) {
  int row = blockIdx.x, tid = threadIdx.x;
  const float4* xr = (const float4*)(x + (size_t)row * LDD);
  short4* xo = (short4*)(xb + (size_t)row * LDD);
  float s = 0.f;
#pragma unroll
  for (int i = 0; i < 4; i++) {
    float4 v = xr[i * 256 + tid];
    s = fmaf(v.x, v.x, s); s = fmaf(v.y, v.y, s);
    s = fmaf(v.z, v.z, s); s = fmaf(v.w, v.w, s);
    short4 o; o.x = f2bf(v.x); o.y = f2bf(v.y); o.z = f2bf(v.z); o.w = f2bf(v.w);
    xo[i * 256 + tid] = o;
  }
#pragma unroll
  for (int off = 32; off > 0; off >>= 1) s += __shfl_down(s, off, 64);
  __shared__ float red[4];
  int lane = tid & 63, wv = tid >> 6;
  if (lane == 0) red[wv] = s;
  __syncthreads();
  if (tid == 0) sq[row] = red[0] + red[1] + red[2] + red[3];
}

// ---- transpose: x fp32 [B,F] -> xT bf16 [F,B], 64x64 LDS tiles ----
__global__ __launch_bounds__(256)
void transpose_bf16(const float* __restrict__ x, short* __restrict__ xT) {
  __shared__ float tile[64][65];
  int bx = blockIdx.x, by = blockIdx.y, tid = threadIdx.x;
  int tr = tid >> 4;          // 0..15
  int tc = (tid & 15) << 2;   // 0,4,..,60
#pragma unroll
  for (int i = 0; i < 4; i++) {
    int r = i * 16 + tr;
    float4 v = *(const float4*)(x + (size_t)(by * 64 + r) * LDD + bx * 64 + tc);
    tile[r][tc + 0] = v.x; tile[r][tc + 1] = v.y;
    tile[r][tc + 2] = v.z; tile[r][tc + 3] = v.w;
  }
  __syncthreads();
#pragma unroll
  for (int i = 0; i < 4; i++) {
    int fr = i * 16 + tr;     // f index within tile
    short4 o;
    o.x = f2bf(tile[tc + 0][fr]); o.y = f2bf(tile[tc + 1][fr]);
    o.z = f2bf(tile[tc + 2][fr]); o.w = f2bf(tile[tc + 3][fr]);
    *(short4*)(xT + (size_t)(bx * 64 + fr) * LDD + by * 64 + tc) = o;
  }
}

// ---- elementwise fp32 -> bf16 convert (W_out) ----
__global__ __launch_bounds__(256)
void conv_bf16(const float* __restrict__ w, short* __restrict__ wb) {
  int i = blockIdx.x * 256 + threadIdx.x;
  float4 v = ((const float4*)w)[i];
  short4 o; o.x = f2bf(v.x); o.y = f2bf(v.y); o.z = f2bf(v.z); o.w = f2bf(v.w);
  ((short4*)wb)[i] = o;
}

#define SB() __builtin_amdgcn_sched_barrier(0)
#define LGKM(n) do { asm volatile("s_waitcnt lgkmcnt(" #n ")" ::: "memory"); SB(); } while (0)

// ============================================================================
// 256x256-tile NT GEMM, register-pipelined (read-one-phase-ahead), 2 barriers
// per K-tile. 512 threads (8 waves 2Mx4N), per-wave 128x64 out, LDS 128KB dbuf,
// chunk-XOR swizzle, counted vmcnt(4)/lgkmcnt(4), setprio around MFMA.
// Phases split along M: each phase = 2 M-frags x 4 N x 2kk = 16 MFMA.
//   bv[4][2] read once per tile (lives whole tile); av double-set X/Y rotates.
//   P_A: rd bv + avY(m23) | stage A0' | lgkm(4) | BAR1 | mfma m01 (avX)
//   P_B: rd avX(m45)      | stage A1' | lgkm(4) |        mfma m23 (avY)
//   P_C: rd avY(m67)      | stage B0''| lgkm(4) |        mfma m45 (avX)
//   P_D: stage B1'' | lgkm(0) | vmcnt(4) | BAR2 | rd avX(m01 of t+1) | mfma m67
// Hazard audit (re-verified R4): BAR1 + lgkm(4) orders all waves' bv reads
// (8 oldest, drained) before B-region staging (P_C/P_D, same buffer t+2 WAR);
// BAR2 after counted vmcnt(4) — per-wave vmcnt drains that wave's A(t+1) and
// B(t+1) stages (oldest 8 of 12), leaving exactly B0/B1(t+2) in flight; all
// A-reads of buffer t drained pre-BAR2 by LGKM(0). Prologue vmcnt(4) drains
// tile-0 fully, leaves B(1) in flight. Uniform control flow (no barrier div).
// MODE 0: gram epilogue (extra=Wrbf, sq); MODE 1: bf16 out; MODE 2: fp32+bias
// ============================================================================
template <int MODE>
__global__ __launch_bounds__(512, 2)
void gemm256(const short* __restrict__ A, const short* __restrict__ Bt,
             short* __restrict__ outB, float* __restrict__ outF,
             const float* __restrict__ extra, const float* __restrict__ sq) {
  __shared__ __attribute__((aligned(16))) char smem[131072];
  const int tid = threadIdx.x;

  // XCD-bijective block swizzle: grid 256 = 16x16, nwg%8==0
  int bid = blockIdx.x;
  int lin = (bid & 7) * 32 + (bid >> 3);
  const int rb = (lin >> 4) * 256;
  const int cb = (lin & 15) * 256;

  // staging: LDS chunk s (16B) of a 128x8-chunk half-tile holds global chunk
  // (r = s>>3, c = (s&7) ^ (r&7)). global src pre-swizzled, LDS dest linear.
  const int s0 = tid, s1 = 512 + tid;
  const int r0 = s0 >> 3, c0 = (s0 & 7) ^ (r0 & 7);
  const int r1 = s1 >> 3, c1 = (s1 & 7) ^ (r1 & 7);
  const size_t go0 = (size_t)r0 * LDD + (size_t)(c0 << 3);
  const size_t go1 = (size_t)r1 * LDD + (size_t)(c1 << 3);

  // half IDs / LDS offsets: 0=B0@0, 1=B1@16K, 2=A0@32K, 3=A1@48K (per buffer)
  const short* gB0 = Bt + (size_t)cb * LDD;
  const short* gB1 = Bt + (size_t)(cb + 128) * LDD;
  const short* gA0 = A + (size_t)rb * LDD;
  const short* gA1 = A + (size_t)(rb + 128) * LDD;
  char* lst = smem + tid * 16;

  auto stage = [&](const short* g, int tt, int half) {
    const short* gp = g + (size_t)tt * 64;
    char* l = lst + ((tt & 1) << 16) + (half << 14);
    async16(gp + go0, l);
    async16(gp + go1, l + 8192);
  };

  // wave/fragment coords
  const int lane = tid & 63;
  const int wv = tid >> 6;        // 0..7
  const int wm = wv >> 2;         // 0..1  (M half)
  const int wn = wv & 3;          // 0..3  (N quarter)
  const int fr = lane & 15;
  const int fq = lane >> 4;
  const int arow = fr * 128;
  const int brow = ((wn & 1) * 64 + fr) * 128;
  const int sx0 = ((fq ^ (fr & 7)) << 4);          // kk=0 chunk, swizzled
  const int sx1 = (((4 + fq) ^ (fr & 7)) << 4);    // kk=1 chunk, swizzled
  const int abase = 32768 + (wm << 14);
  const int bbase = (wn >> 1) << 14;

  f32x4 acc[8][4];
#pragma unroll
  for (int m = 0; m < 8; ++m)
#pragma unroll
    for (int n = 0; n < 4; ++n) acc[m][n] = {0.f, 0.f, 0.f, 0.f};

  // av byte offsets within A-half: m-frag pair P -> P*4096 (P=0:m01,1:m23,...)
#define RD_AV(dst, base_off, ap)                                        \
  do {                                                                  \
    dst[0][0] = *(const short8*)((ap) + (base_off) + arow + sx0);       \
    dst[0][1] = *(const short8*)((ap) + (base_off) + arow + sx1);       \
    dst[1][0] = *(const short8*)((ap) + (base_off) + 2048 + arow + sx0);\
    dst[1][1] = *(const short8*)((ap) + (base_off) + 2048 + arow + sx1);\
  } while (0)

#define MM(av2, mb)                                                     \
  do {                                                                  \
    __builtin_amdgcn_s_setprio(1);                                      \
    _Pragma("unroll")                                                   \
    for (int kk = 0; kk < 2; ++kk)                                      \
      _Pragma("unroll")                                                 \
      for (int mi = 0; mi < 2; ++mi)                                    \
        _Pragma("unroll")                                               \
        for (int n = 0; n < 4; ++n)                                     \
          acc[(mb) + mi][n] = __builtin_amdgcn_mfma_f32_16x16x32_bf16(  \
              av2[mi][kk], bv[n][kk], acc[(mb) + mi][n], 0, 0, 0);      \
    __builtin_amdgcn_s_setprio(0);                                      \
  } while (0)

  short8 avX[2][2], avY[2][2], bv[4][2];

  // prologue: tile0 fully + tile1 B halves; prime avX(m01) of tile 0
  stage(gB0, 0, 0); stage(gB1, 0, 1); stage(gA0, 0, 2); stage(gA1, 0, 3);
  stage(gB0, 1, 0); stage(gB1, 1, 1);
  asm volatile("s_waitcnt vmcnt(4)" ::: "memory");
  __builtin_amdgcn_s_barrier();
  RD_AV(avX, 0, smem + abase);
  SB();

  for (int t = 0; t < NT; ++t) {
    const int bufo = (t & 1) << 16;
    const char* ab = smem + bufo + abase;
    const char* bb = smem + bufo + bbase;
    const char* abn = smem + (bufo ^ (1 << 16)) + abase;

    // ---- P_A: rd bv(8) + avY m23(4); stage A0(t+1); BAR1; mfma m01 ----
#pragma unroll
    for (int n = 0; n < 4; ++n) {
      bv[n][0] = *(const short8*)(bb + brow + n * 2048 + sx0);
      bv[n][1] = *(const short8*)(bb + brow + n * 2048 + sx1);
    }
    SB();
    RD_AV(avY, 4096, ab);
    SB();
    if (t + 1 < NT) stage(gA0, t + 1, 2);
    LGKM(4);                       // drains avX(m01) + bv; avY in flight
    __builtin_amdgcn_s_barrier();  // BAR1: all bv reads done -> B staging safe
    MM(avX, 0);                    // m0,1

    // ---- P_B: rd avX m45(4); stage A1(t+1); mfma m23 ----
    RD_AV(avX, 8192, ab);
    SB();
    if (t + 1 < NT) stage(gA1, t + 1, 3);
    LGKM(4);                       // drains avY(m23); avX(m45) in flight
    MM(avY, 2);                    // m2,3

    // ---- P_C: rd avY m67(4); stage B0(t+2); mfma m45 ----
    RD_AV(avY, 8192 + 4096, ab);
    SB();
    if (t + 2 < NT) stage(gB0, t + 2, 0);
    LGKM(4);                       // drains avX(m45); avY(m67) in flight
    MM(avX, 4);                    // m4,5

    // ---- P_D: stage B1(t+2); lgkm(0); vmcnt; BAR2; rd avX m01(t+1); mfma m67
    if (t + 2 < NT) stage(gB1, t + 2, 1);
    LGKM(0);                       // drains avY(m67) pre-BAR2 (WAR safety)
    if (t + 2 < NT) asm volatile("s_waitcnt vmcnt(4)" ::: "memory");
    else            asm volatile("s_waitcnt vmcnt(0)" ::: "memory");
    __builtin_amdgcn_s_barrier();  // BAR2: buffer t+1 globally staged
    if (t + 1 < NT) { RD_AV(avX, 0, abn); }   // m0,1 of t+1 (drains under m67)
    SB();
    MM(avY, 6);                    // m6,7
  }

  // ---- epilogue ----
  const int orow = rb + wm * 128 + fq * 4;   // + m*16 + rr
  const int ocol = cb + wn * 64 + fr;        // + n*16
  if (MODE == 0) {
    float sqc[4];
#pragma unroll
    for (int n = 0; n < 4; ++n) sqc[n] = sq[ocol + n * 16];
#pragma unroll
    for (int m = 0; m < 8; ++m) {
#pragma unroll
      for (int rr = 0; rr < 4; ++rr) {
        int row = orow + m * 16 + rr;
        float sqr = sq[row];
#pragma unroll
        for (int n = 0; n < 4; ++n) {
          size_t idx = (size_t)row * LDD + ocol + n * 16;
          float d2 = sqr + sqc[n] - 2.0f * acc[m][n][rr];
          float d = sqrtf(fmaxf(d2, 0.f));
          outB[idx] = f2bf(__expf(-fabsf(extra[idx]) * d));
        }
      }
    }
  } else if (MODE == 1) {
#pragma unroll
    for (int m = 0; m < 8; ++m)
#pragma unroll
      for (int rr = 0; rr < 4; ++rr) {
        int row = orow + m * 16 + rr;
#pragma unroll
        for (int n = 0; n < 4; ++n)
          outB[(size_t)row * LDD + ocol + n * 16] = f2bf(acc[m][n][rr]);
      }
  } else {
    float bc[4];
#pragma unroll
    for (int n = 0; n < 4; ++n) bc[n] = extra[ocol + n * 16];
#pragma unroll
    for (int m = 0; m < 8; ++m)
#pragma unroll
      for (int rr = 0; rr < 4; ++rr) {
        int row = orow + m * 16 + rr;
#pragma unroll
        for (int n = 0; n < 4; ++n)
          outF[(size_t)row * LDD + ocol + n * 16] = acc[m][n][rr] + bc[n];
      }
  }
#undef RD_AV
#undef MM
}

extern "C" void kernel_launch(void* const* d_in, const int* in_sizes, int n_in,
                              void* d_out, int out_size, void* d_ws, size_t ws_size,
                              hipStream_t stream) {
  const float* x    = (const float*)d_in[0];
  const float* Wrbf = (const float*)d_in[1];
  const float* Wout = (const float*)d_in[2];
  const float* bout = (const float*)d_in[3];
  float* out = (float*)d_out;

  char* ws = (char*)d_ws;
  short* xb    = (short*)ws;                               // 32 MB
  float* sq    = (float*)(ws + (size_t)32 * 1024 * 1024);  // 16 KB
  short* woutb = (short*)(ws + (size_t)32 * 1024 * 1024);  // 32 MB (after gram)
  short* gram  = (short*)d_out;                            // 32 MB
  short* xT    = (short*)((char*)d_out + (size_t)32 * 1024 * 1024);  // 32 MB
  short* mixed = xb;                                       // reuse after gram

  prep_rows<<<LDD, 256, 0, stream>>>(x, xb, sq);
  transpose_bf16<<<dim3(64, 64), 256, 0, stream>>>(x, xT);
  // gram[i,j] = exp(-|Wrbf[i,j]| * ||x_i - x_j||)  (full grid, fused epilogue)
  gemm256<0><<<256, 512, 0, stream>>>(xb, xb, gram, nullptr, Wrbf, sq);
  // mixed = gram @ x   (B^T operand = xT)
  gemm256<1><<<256, 512, 0, stream>>>(gram, xT, mixed, nullptr, nullptr, nullptr);
  conv_bf16<<<LDD * LDD / 4 / 256, 256, 0, stream>>>(Wout, woutb);
  // out = mixed @ W_out^T + b_out
  gemm256<2><<<256, 512, 0, stream>>>(mixed, woutb, nullptr, out, bout, nullptr);
}